// Round 1
// baseline (772.087 us; speedup 1.0000x reference)
//
#include <hip/hip_runtime.h>

#define C_DIM 768
#define TOK 32

// LDS union: stage-1 (x chunk + Wa chunk) overlaps stage-2 (Wb chunk)
union SmemU {
  struct {
    float xs[TOK][36];    // x[t][k] chunk, row stride 36 (144B, 16B-aligned)
    float was[192][34];   // Wa[o][k] chunk, rows 168..191 zero; stride 34 -> 2-way banks on b64
  } s1;
  float wbs[56][128];     // Wb[k=e*8+r][c] chunk
};

__global__ __launch_bounds__(256) void moe_main(
    const float* __restrict__ x, const float* __restrict__ wg,
    const float* __restrict__ Wa, const float* __restrict__ Wb,
    float* __restrict__ out, unsigned int* __restrict__ counts, int T)
{
  __shared__ SmemU u;
  __shared__ float hs[TOK][168];   // h[t][o], o = a*56 + e*8 + r
  __shared__ float ls[TOK][8];     // gating logits
  __shared__ float cf[TOK][8];     // hierarchy coefficients per token

  const int tid = threadIdx.x;
  const int t0 = blockIdx.x * TOK;
  const int og = tid & 31;   // output-group lane
  const int tg = tid >> 5;   // token group (0..7)

  // -------- Stage 1: h[t][o] = sum_c x[t][c] * Wa[o][c], fused gating --------
  float acc1[4][6];
  #pragma unroll
  for (int jt = 0; jt < 4; ++jt)
    #pragma unroll
    for (int m = 0; m < 6; ++m) acc1[jt][m] = 0.f;

  float lg = 0.f;
  const int gt = tid / 7;        // token for gating lane (valid tid<224)
  const int ge = tid - gt * 7;   // expert for gating lane

  for (int kc = 0; kc < C_DIM; kc += 32) {
    __syncthreads();
    // stage x chunk: 32 tok x 8 float4 = 256 f4, one per thread
    {
      const int t = tid >> 3, kq = tid & 7;
      const float4 v = *(const float4*)(x + (size_t)(t0 + t) * C_DIM + kc + kq * 4);
      *(float4*)&u.s1.xs[t][kq * 4] = v;
    }
    // stage Wa chunk: 192 rows x 8 f4 (rows >=168 zero-padded)
    #pragma unroll
    for (int i = 0; i < 6; ++i) {
      const int idx = tid + i * 256;
      const int o = idx >> 3, kq = idx & 7;
      float4 v = make_float4(0.f, 0.f, 0.f, 0.f);
      if (o < 168) v = *(const float4*)(Wa + (size_t)o * C_DIM + kc + kq * 4);
      // row stride 34 floats (136B) is only 8B-aligned -> write as 2x float2
      *(float2*)&u.s1.was[o][kq * 4]     = make_float2(v.x, v.y);
      *(float2*)&u.s1.was[o][kq * 4 + 2] = make_float2(v.z, v.w);
    }
    __syncthreads();

    // gating partial dot (224 active lanes; w_gate is 21.5KB, L1/L2-resident)
    if (tid < 224) {
      #pragma unroll
      for (int k = 0; k < 32; ++k)
        lg = fmaf(u.s1.xs[gt][k], wg[(kc + k) * 7 + ge], lg);
    }

    // register-tiled GEMM1: 4 tokens x 6 outputs per thread
    #pragma unroll
    for (int k = 0; k < 32; k += 4) {
      float4 xv[4];
      #pragma unroll
      for (int jt = 0; jt < 4; ++jt)
        xv[jt] = *(const float4*)&u.s1.xs[tg + 8 * jt][k];
      #pragma unroll
      for (int m = 0; m < 6; ++m) {
        const int o = og + 32 * m;
        const float2 w0 = *(const float2*)&u.s1.was[o][k];
        const float2 w1 = *(const float2*)&u.s1.was[o][k + 2];
        #pragma unroll
        for (int jt = 0; jt < 4; ++jt)
          acc1[jt][m] += xv[jt].x * w0.x + xv[jt].y * w0.y
                       + xv[jt].z * w1.x + xv[jt].w * w1.y;
      }
    }
  }

  // write logits + h to LDS
  if (tid < 224) ls[gt][ge] = lg;
  #pragma unroll
  for (int jt = 0; jt < 4; ++jt) {
    const int t = tg + 8 * jt;
    #pragma unroll
    for (int m = 0; m < 6; ++m) {
      const int o = og + 32 * m;
      if (o < 168) hs[t][o] = acc1[jt][m];
    }
  }
  __syncthreads();

  // argmax (top-1 gate == 1.0 exactly), counts, hierarchy coefficients
  if (tid < TOK) {
    float best = ls[tid][0]; int be = 0;
    #pragma unroll
    for (int e = 1; e < 7; ++e)
      if (ls[tid][e] > best) { best = ls[tid][e]; be = e; }  // strict > = lowest-index tie-break
    atomicAdd(&counts[be], 1u);
    float c[7] = {0.f, 0.f, 0.f, 0.f, 0.f, 0.f, 0.f};
    c[be] = 1.f;
    if (be >= 4) { c[0] = c[1] = c[2] = c[3] = 0.25f; }
    if (be == 6) { c[4] = 0.5f; c[5] = 0.5f; }
    #pragma unroll
    for (int e = 0; e < 7; ++e) cf[tid][e] = c[e];
  }
  __syncthreads();

  // scale h by coefficients in place
  for (int i = tid; i < TOK * 168; i += 256) {
    const int t = i / 168, o = i - t * 168;
    const int e = (o % 56) >> 3;
    hs[t][o] *= cf[t][e];
  }
  // (stage-2 loop-top barrier covers the scale->read and was->wbs hazards)

  // -------- Stage 2: y[a][t][c] = sum_k hs[t][a*56+k] * Wb[a][k][c] --------
  const int cg = tid & 31, tg2 = tid >> 5;
  for (int a = 0; a < 3; ++a) {
    const int hb = a * 56;
    for (int c0 = 0; c0 < C_DIM; c0 += 128) {
      __syncthreads();
      // stage Wb chunk: wbs[k][c] = Wb[a][e][c0+c][r]; gather stride 32B (L2-resident, 516KB total)
      #pragma unroll
      for (int i = 0; i < 28; ++i) {
        const int idx = tid + i * 256;
        const int k = idx >> 7, c = idx & 127;
        const int e = k >> 3, r = k & 7;
        u.wbs[k][c] = Wb[((size_t)(a * 7 + e) * C_DIM + c0 + c) * 8 + r];
      }
      __syncthreads();

      float acc2[4][4];
      #pragma unroll
      for (int jt = 0; jt < 4; ++jt)
        #pragma unroll
        for (int jc = 0; jc < 4; ++jc) acc2[jt][jc] = 0.f;

      #pragma unroll
      for (int k = 0; k < 56; k += 4) {
        float hf[4][4];
        #pragma unroll
        for (int jt = 0; jt < 4; ++jt) {
          const float4 h4 = *(const float4*)&hs[tg2 + 8 * jt][hb + k];
          hf[jt][0] = h4.x; hf[jt][1] = h4.y; hf[jt][2] = h4.z; hf[jt][3] = h4.w;
        }
        #pragma unroll
        for (int kk = 0; kk < 4; ++kk) {
          const float4 wv = *(const float4*)&u.wbs[k + kk][cg * 4];
          #pragma unroll
          for (int jt = 0; jt < 4; ++jt) {
            acc2[jt][0] += hf[jt][kk] * wv.x;
            acc2[jt][1] += hf[jt][kk] * wv.y;
            acc2[jt][2] += hf[jt][kk] * wv.z;
            acc2[jt][3] += hf[jt][kk] * wv.w;
          }
        }
      }

      // coalesced float4 stores
      #pragma unroll
      for (int jt = 0; jt < 4; ++jt) {
        const int t = tg2 + 8 * jt;
        const float4 v = make_float4(acc2[jt][0], acc2[jt][1], acc2[jt][2], acc2[jt][3]);
        *(float4*)(out + ((size_t)a * T + (t0 + t)) * C_DIM + c0 + cg * 4) = v;
      }
    }
  }
}

// loss = cv2(importance) + cv2(load); with K=1 both equal the per-expert counts
__global__ void loss_k(const unsigned int* __restrict__ counts,
                       float* __restrict__ out, int T)
{
  if (threadIdx.x == 0) {
    float c[7], mean = 0.f;
    #pragma unroll
    for (int e = 0; e < 7; ++e) { c[e] = (float)counts[e]; mean += c[e]; }
    mean *= (1.f / 7.f);
    float var = 0.f;
    #pragma unroll
    for (int e = 0; e < 7; ++e) { const float d = c[e] - mean; var += d * d; }
    var *= (1.f / 6.f);  // ddof=1
    const float cv = var / (mean * mean + 1e-10f);
    out[(size_t)3 * T * C_DIM] = 2.f * cv;
  }
}

extern "C" void kernel_launch(void* const* d_in, const int* in_sizes, int n_in,
                              void* d_out, int out_size, void* d_ws, size_t ws_size,
                              hipStream_t stream)
{
  const float* x  = (const float*)d_in[0];
  const float* wg = (const float*)d_in[1];
  const float* Wa = (const float*)d_in[2];
  const float* Wb = (const float*)d_in[3];
  float* out = (float*)d_out;
  unsigned int* counts = (unsigned int*)d_ws;

  const int T = in_sizes[0] / C_DIM;  // 16384

  hipMemsetAsync(counts, 0, 8 * sizeof(unsigned int), stream);
  moe_main<<<dim3(T / TOK), dim3(256), 0, stream>>>(x, wg, Wa, Wb, out, counts, T);
  loss_k<<<dim3(1), dim3(64), 0, stream>>>(counts, out, T);
}

// Round 2
// 576.503 us; speedup vs baseline: 1.3393x; 1.3393x over previous
//
#include <hip/hip_runtime.h>

#define C_DIM 768
#define TOK 32     // tokens per block (4 waves x 8 tokens)
#define KC 64      // k-chunk staged in LDS for x

// d_ws layout:
//   [0)       8 x uint counts
//   [1024)    WaT4: granule (k4, o) -> float4 {Wa[o][4k4..4k4+3]}, o-stride 1, k4-stride 192
//             o in [0,168): Wa rows (a*56+e*8+r); o in [168,175): w_gate col e; else 0
//             192*192 granules = 589824 B
//   [590848)  WbT4: granule (ak, c4) -> float4 {WbT[a][k][4c4..+3]}, ak = a*56+k
//             168*192 granules = 516096 B

__device__ __forceinline__ void fma4(float4& a, const float4 b, const float s) {
  a.x = fmaf(b.x, s, a.x); a.y = fmaf(b.y, s, a.y);
  a.z = fmaf(b.z, s, a.z); a.w = fmaf(b.w, s, a.w);
}

__global__ __launch_bounds__(256) void transpose_wa(
    const float* __restrict__ wa, const float* __restrict__ wg,
    float4* __restrict__ waT4) {
  const int g = blockIdx.x * 256 + threadIdx.x;   // 192*192 = 36864
  const int o = g % 192, k4 = g / 192;
  float4 v = make_float4(0.f, 0.f, 0.f, 0.f);
  if (o < 168) {
    v = *(const float4*)(wa + (size_t)o * C_DIM + k4 * 4);
  } else if (o < 175) {
    const int e = o - 168;
    v.x = wg[(k4 * 4 + 0) * 7 + e];
    v.y = wg[(k4 * 4 + 1) * 7 + e];
    v.z = wg[(k4 * 4 + 2) * 7 + e];
    v.w = wg[(k4 * 4 + 3) * 7 + e];
  }
  waT4[g] = v;   // coalesced (o fastest)
}

__global__ __launch_bounds__(256) void transpose_wb(
    const float* __restrict__ wb, float4* __restrict__ wbT4) {
  const int g = blockIdx.x * 256 + threadIdx.x;   // 168*192 = 32256
  const int c4 = g % 192, ak = g / 192;
  const int a = ak / 56, k = ak - a * 56;
  const int e = k >> 3, r = k & 7;
  const float* s = wb + ((size_t)(a * 7 + e) * C_DIM + c4 * 4) * 8 + r;
  wbT4[g] = make_float4(s[0], s[8], s[16], s[24]);  // gather stride 32B; write coalesced
}

__global__ __launch_bounds__(256, 2) void moe_main(
    const float* __restrict__ x, const float4* __restrict__ waT4,
    const float4* __restrict__ wbT4, float* __restrict__ out,
    unsigned int* __restrict__ counts, int T) {
  // xs: wave-private x stage -> written and read by the SAME wave, no barriers.
  __shared__ float xs[4][8][KC];      // 8 KB, lane-linear writes = conflict-free
  __shared__ float hsT[168][36];      // h transposed [o][tok], stride 36 (144B, 16B-aligned)

  const int tid = threadIdx.x;
  const int w = tid >> 6, lane = tid & 63;
  const int t0 = blockIdx.x * TOK;
  const int tb = w * 8;               // this wave's first token (block-local)

  // ---- Stage 1: h[t][o] = sum_k x[t][k]*WaT[o][k]; o = lane + 64m (m=0..2) ----
  float4 acc[8][3];
  #pragma unroll
  for (int t = 0; t < 8; ++t)
    #pragma unroll
    for (int m = 0; m < 3; ++m) acc[t][m] = make_float4(0.f, 0.f, 0.f, 0.f);

  const int xt = lane >> 3;           // staging row (0..7)
  const int xc = (lane & 7) * 8;      // staging col start

  for (int kc = 0; kc < C_DIM; kc += KC) {
    // stage this wave's 8 tokens x KC floats: contiguous, coalesced, no barrier
    const float* xsrc = x + (size_t)(t0 + tb + xt) * C_DIM + kc + xc;
    *(float4*)&xs[w][xt][xc]     = *(const float4*)(xsrc);
    *(float4*)&xs[w][xt][xc + 4] = *(const float4*)(xsrc + 4);
    // (compiler inserts lgkmcnt wait before dependent ds_read; same-wave only)

    #pragma unroll
    for (int kk = 0; kk < KC; kk += 4) {
      const int k4g = (kc + kk) >> 2;
      const float4* wrow = waT4 + (size_t)k4g * 192 + lane;
      const float4 wa0 = wrow[0];      // o = lane
      const float4 wa1 = wrow[64];     // o = lane + 64
      const float4 wa2 = wrow[128];    // o = lane + 128
      #pragma unroll
      for (int t = 0; t < 8; ++t) {
        const float4 xv = *(const float4*)&xs[w][t][kk];   // broadcast read (free)
        acc[t][0].x = fmaf(xv.x, wa0.x, acc[t][0].x);
        acc[t][0].y = fmaf(xv.y, wa0.y, acc[t][0].y);
        acc[t][0].z = fmaf(xv.z, wa0.z, acc[t][0].z);
        acc[t][0].w = fmaf(xv.w, wa0.w, acc[t][0].w);
        acc[t][1].x = fmaf(xv.x, wa1.x, acc[t][1].x);
        acc[t][1].y = fmaf(xv.y, wa1.y, acc[t][1].y);
        acc[t][1].z = fmaf(xv.z, wa1.z, acc[t][1].z);
        acc[t][1].w = fmaf(xv.w, wa1.w, acc[t][1].w);
        acc[t][2].x = fmaf(xv.x, wa2.x, acc[t][2].x);
        acc[t][2].y = fmaf(xv.y, wa2.y, acc[t][2].y);
        acc[t][2].z = fmaf(xv.z, wa2.z, acc[t][2].z);
        acc[t][2].w = fmaf(xv.w, wa2.w, acc[t][2].w);
      }
    }
  }

  // horizontal sums
  float h[8][3];
  #pragma unroll
  for (int t = 0; t < 8; ++t)
    #pragma unroll
    for (int m = 0; m < 3; ++m)
      h[t][m] = (acc[t][m].x + acc[t][m].y) + (acc[t][m].z + acc[t][m].w);

  // logits live in lanes 40..46 at m=2 (o = 168+e). shfl-broadcast, argmax per token.
  int be[8];
  #pragma unroll
  for (int t = 0; t < 8; ++t) {
    float best = __shfl(h[t][2], 40);
    int b = 0;
    #pragma unroll
    for (int e = 1; e < 7; ++e) {
      const float lv = __shfl(h[t][2], 40 + e);
      if (lv > best) { best = lv; b = e; }   // strict > = lowest-index tie-break
    }
    be[t] = b;
  }
  if (lane == 0) {
    #pragma unroll
    for (int t = 0; t < 8; ++t) atomicAdd(&counts[be[t]], 1u);
  }

  // scale by hierarchy coefficient and write h transposed
  #pragma unroll
  for (int m = 0; m < 3; ++m) {
    const int o = lane + 64 * m;
    if (o < 168) {
      const int e = (o % 56) >> 3;
      #pragma unroll
      for (int t = 0; t < 8; ++t) {
        const int b = be[t];
        float co = (e == b) ? 1.f : 0.f;
        if (b >= 4 && e < 4) co += 0.25f;
        if (b == 6 && (e == 4 || e == 5)) co += 0.5f;
        hsT[o][tb + t] = h[t][m] * co;
      }
    }
  }
  __syncthreads();   // the ONE barrier: hsT producer -> consumer

  // ---- Stage 2: y[a][t][c] = sum_k hsT[a*56+k][t] * WbT[a][k][c] ----
  for (int a = 0; a < 3; ++a) {
    float4 acc2[3][8];
    #pragma unroll
    for (int cc = 0; cc < 3; ++cc)
      #pragma unroll
      for (int t = 0; t < 8; ++t) acc2[cc][t] = make_float4(0.f, 0.f, 0.f, 0.f);

    #pragma unroll 8
    for (int k = 0; k < 56; ++k) {
      const int o = a * 56 + k;
      const float4* wrow = wbT4 + (size_t)o * 192 + lane;
      const float4 wb0 = wrow[0];
      const float4 wb1 = wrow[64];
      const float4 wb2 = wrow[128];
      const float4 h0 = *(const float4*)&hsT[o][tb];       // broadcast b128 (free)
      const float4 h1 = *(const float4*)&hsT[o][tb + 4];
      const float hv[8] = {h0.x, h0.y, h0.z, h0.w, h1.x, h1.y, h1.z, h1.w};
      #pragma unroll
      for (int t = 0; t < 8; ++t) {
        const float s = hv[t];
        fma4(acc2[0][t], wb0, s);
        fma4(acc2[1][t], wb1, s);
        fma4(acc2[2][t], wb2, s);
      }
    }

    #pragma unroll
    for (int cc = 0; cc < 3; ++cc)
      #pragma unroll
      for (int t = 0; t < 8; ++t)
        *(float4*)(out + ((size_t)a * T + t0 + tb + t) * C_DIM + cc * 256 + lane * 4)
            = acc2[cc][t];
  }
}

// loss = 2 * cv2(counts)  (importance == load == counts when K=1, gate==1.0)
__global__ void loss_k(const unsigned int* __restrict__ counts,
                       float* __restrict__ out, int T) {
  if (threadIdx.x == 0) {
    float c[7], mean = 0.f;
    #pragma unroll
    for (int e = 0; e < 7; ++e) { c[e] = (float)counts[e]; mean += c[e]; }
    mean *= (1.f / 7.f);
    float var = 0.f;
    #pragma unroll
    for (int e = 0; e < 7; ++e) { const float d = c[e] - mean; var += d * d; }
    var *= (1.f / 6.f);  // ddof=1
    out[(size_t)3 * T * C_DIM] = 2.f * (var / (mean * mean + 1e-10f));
  }
}

extern "C" void kernel_launch(void* const* d_in, const int* in_sizes, int n_in,
                              void* d_out, int out_size, void* d_ws, size_t ws_size,
                              hipStream_t stream) {
  const float* x  = (const float*)d_in[0];
  const float* wg = (const float*)d_in[1];
  const float* Wa = (const float*)d_in[2];
  const float* Wb = (const float*)d_in[3];
  float* out = (float*)d_out;

  unsigned int* counts = (unsigned int*)d_ws;
  float4* waT4 = (float4*)((char*)d_ws + 1024);
  float4* wbT4 = (float4*)((char*)d_ws + 590848);

  const int T = in_sizes[0] / C_DIM;  // 16384

  hipMemsetAsync(counts, 0, 8 * sizeof(unsigned int), stream);
  transpose_wa<<<dim3(144), dim3(256), 0, stream>>>(Wa, wg, waT4);
  transpose_wb<<<dim3(126), dim3(256), 0, stream>>>(Wb, wbT4);
  moe_main<<<dim3(T / TOK), dim3(256), 0, stream>>>(x, waT4, wbT4, out, counts, T);
  loss_k<<<dim3(1), dim3(64), 0, stream>>>(counts, out, T);
}

// Round 3
// 403.579 us; speedup vs baseline: 1.9131x; 1.4285x over previous
//
#include <hip/hip_runtime.h>

#define C_DIM 768

// d_ws layout:
//   [0)       8 x uint counts
//   [1024)    WaT4: granule (k4, o) -> float4 {Wa[o][4k4..4k4+3]}, g = k4*192 + o
//             o in [0,168): Wa rows (a*56+e*8+r); o in [168,175): w_gate col e; else 0
//   [590848)  WbT4: granule (o, c4) -> float4 {WbT[o][4c4..+3]}, g = o*192 + c4, o = a*56+k

__global__ __launch_bounds__(256) void transpose_wa(
    const float* __restrict__ wa, const float* __restrict__ wg,
    float4* __restrict__ waT4) {
  const int g = blockIdx.x * 256 + threadIdx.x;   // 192*192 = 36864
  const int o = g % 192, k4 = g / 192;
  float4 v = make_float4(0.f, 0.f, 0.f, 0.f);
  if (o < 168) {
    v = *(const float4*)(wa + (size_t)o * C_DIM + k4 * 4);
  } else if (o < 175) {
    const int e = o - 168;
    v.x = wg[(k4 * 4 + 0) * 7 + e];
    v.y = wg[(k4 * 4 + 1) * 7 + e];
    v.z = wg[(k4 * 4 + 2) * 7 + e];
    v.w = wg[(k4 * 4 + 3) * 7 + e];
  }
  waT4[g] = v;
}

__global__ __launch_bounds__(256) void transpose_wb(
    const float* __restrict__ wb, float4* __restrict__ wbT4) {
  const int g = blockIdx.x * 256 + threadIdx.x;   // 168*192 = 32256
  const int c4 = g % 192, ak = g / 192;
  const int a = ak / 56, k = ak - a * 56;
  const int e = k >> 3, r = k & 7;
  const float* s = wb + ((size_t)(a * 7 + e) * C_DIM + c4 * 4) * 8 + r;
  wbT4[g] = make_float4(s[0], s[8], s[16], s[24]);
}

__global__ __launch_bounds__(256, 2) void moe_main(
    const float* __restrict__ x, const float4* __restrict__ waT4,
    const float4* __restrict__ wbT4, float* __restrict__ out,
    unsigned int* __restrict__ counts, int T) {
  __shared__ float xs[4][2][8][64];   // per-wave double-buffered x chunk (16 KB)
  __shared__ float hsT[168][36];      // h^T [o][tok], stride 36 (16B-aligned cols)

  const int tid = threadIdx.x;
  const int w = tid >> 6, lane = tid & 63;
  const int half = lane >> 5, l5 = lane & 31;
  const int t0 = blockIdx.x * 32;
  const int tb = w * 8;

  // ---------------- Stage 1: h = x @ WaT (+ gating logits) ----------------
  // lane-half token split: half h owns tokens [h*4, h*4+4); lane covers
  // o = l5 + 32m, m=0..5 (o in 0..191; rows >=175 are zero-padded).
  float acc1[4][6];
  #pragma unroll
  for (int tl = 0; tl < 4; ++tl)
    #pragma unroll
    for (int m = 0; m < 6; ++m) acc1[tl][m] = 0.f;

  const int xt = lane >> 3, xc = (lane & 7) * 8;
  const float* xbase = x + (size_t)(t0 + tb + xt) * C_DIM + xc;
  const float4* wa_l = waT4 + l5;

  // warmup: chunk 0 staged, chunk 1 in regs, weight steps 0,1 in flight
  float4 xr0 = *(const float4*)(xbase);
  float4 xr1 = *(const float4*)(xbase + 4);
  *(float4*)&xs[w][0][xt][xc]     = xr0;
  *(float4*)&xs[w][0][xt][xc + 4] = xr1;
  xr0 = *(const float4*)(xbase + 64);
  xr1 = *(const float4*)(xbase + 68);

  float4 wv[2][6];
  #pragma unroll
  for (int m = 0; m < 6; ++m) wv[0][m] = wa_l[32 * m];
  #pragma unroll
  for (int m = 0; m < 6; ++m) wv[1][m] = wa_l[192 + 32 * m];

  #pragma unroll 1
  for (int ch = 0; ch < 12; ++ch) {
    // hand next chunk to LDS, issue load for chunk+2
    if (ch < 11) {
      *(float4*)&xs[w][(ch + 1) & 1][xt][xc]     = xr0;
      *(float4*)&xs[w][(ch + 1) & 1][xt][xc + 4] = xr1;
      if (ch < 10) {
        xr0 = *(const float4*)(xbase + (ch + 2) * 64);
        xr1 = *(const float4*)(xbase + (ch + 2) * 64 + 4);
      }
    }
    const int buf = ch & 1;
    #pragma unroll
    for (int kk = 0; kk < 16; ++kk) {
      const int p = kk & 1;   // (ch*16+kk)&1 == kk&1 since 16 is even
      float4 xv[4];
      #pragma unroll
      for (int tl = 0; tl < 4; ++tl)
        xv[tl] = *(const float4*)&xs[w][buf][half * 4 + tl][kk * 4];
      #pragma unroll
      for (int m = 0; m < 6; ++m) {
        const float4 wvv = wv[p][m];
        #pragma unroll
        for (int tl = 0; tl < 4; ++tl) {
          float s = acc1[tl][m];
          s = fmaf(xv[tl].x, wvv.x, s);
          s = fmaf(xv[tl].y, wvv.y, s);
          s = fmaf(xv[tl].z, wvv.z, s);
          s = fmaf(xv[tl].w, wvv.w, s);
          acc1[tl][m] = s;
        }
      }
      // prefetch weights for step+2 into the buffer just consumed (clamped tail)
      int gn = ch * 16 + kk + 2;
      gn = gn > 191 ? 191 : gn;
      #pragma unroll
      for (int m = 0; m < 6; ++m) wv[p][m] = wa_l[(size_t)gn * 192 + 32 * m];
    }
  }

  // ---- argmax over logits (o=168+e -> m=5, l5=8+e, same half), counts ----
  int be[4];
  #pragma unroll
  for (int tl = 0; tl < 4; ++tl) {
    float best = __shfl(acc1[tl][5], (lane & 32) + 8);
    int b = 0;
    #pragma unroll
    for (int e = 1; e < 7; ++e) {
      const float lv = __shfl(acc1[tl][5], (lane & 32) + 8 + e);
      if (lv > best) { best = lv; b = e; }   // strict > = lowest-index tie-break
    }
    be[tl] = b;
  }
  if (l5 == 0) {
    #pragma unroll
    for (int tl = 0; tl < 4; ++tl) atomicAdd(&counts[be[tl]], 1u);
  }

  // ---- scale by hierarchy coefficient, write h^T (same-wave consumer) ----
  #pragma unroll
  for (int tl = 0; tl < 4; ++tl) {
    const int b = be[tl];
    const int tcol = tb + half * 4 + tl;
    #pragma unroll
    for (int m = 0; m < 6; ++m) {
      const int o = l5 + 32 * m;
      if (o < 168) {
        const int e = (o % 56) >> 3;
        float co = (e == b) ? 1.f : 0.f;
        if (b >= 4 && e < 4) co += 0.25f;
        if (b == 6 && (e == 4 || e == 5)) co += 0.5f;
        hsT[o][tcol] = acc1[tl][m] * co;
      }
    }
  }
  // no __syncthreads: each wave reads only its own hsT columns below

  // ---------------- Stage 2: y[a] = h[a] @ WbT[a] ----------------
  const float4* wb_l = wbT4 + lane;
  float4 u[2][3], hb[2][2];
  #pragma unroll
  for (int cc = 0; cc < 3; ++cc) {
    u[0][cc] = wb_l[64 * cc];
    u[1][cc] = wb_l[192 + 64 * cc];
  }
  hb[0][0] = *(const float4*)&hsT[0][tb];
  hb[0][1] = *(const float4*)&hsT[0][tb + 4];
  hb[1][0] = *(const float4*)&hsT[1][tb];
  hb[1][1] = *(const float4*)&hsT[1][tb + 4];

  #pragma unroll 1
  for (int a = 0; a < 3; ++a) {
    float4 acc2[3][8];
    #pragma unroll
    for (int cc = 0; cc < 3; ++cc)
      #pragma unroll
      for (int t = 0; t < 8; ++t) acc2[cc][t] = make_float4(0.f, 0.f, 0.f, 0.f);

    #pragma unroll 4
    for (int kq = 0; kq < 56; ++kq) {
      const int o = a * 56 + kq;
      const int p = kq & 1;   // (a*56+kq)&1 == kq&1 since 56 is even
      const float hv[8] = {hb[p][0].x, hb[p][0].y, hb[p][0].z, hb[p][0].w,
                           hb[p][1].x, hb[p][1].y, hb[p][1].z, hb[p][1].w};
      const float4 w0 = u[p][0], w1 = u[p][1], w2 = u[p][2];
      #pragma unroll
      for (int t = 0; t < 8; ++t) {
        const float s = hv[t];
        acc2[0][t].x = fmaf(w0.x, s, acc2[0][t].x);
        acc2[0][t].y = fmaf(w0.y, s, acc2[0][t].y);
        acc2[0][t].z = fmaf(w0.z, s, acc2[0][t].z);
        acc2[0][t].w = fmaf(w0.w, s, acc2[0][t].w);
        acc2[1][t].x = fmaf(w1.x, s, acc2[1][t].x);
        acc2[1][t].y = fmaf(w1.y, s, acc2[1][t].y);
        acc2[1][t].z = fmaf(w1.z, s, acc2[1][t].z);
        acc2[1][t].w = fmaf(w1.w, s, acc2[1][t].w);
        acc2[2][t].x = fmaf(w2.x, s, acc2[2][t].x);
        acc2[2][t].y = fmaf(w2.y, s, acc2[2][t].y);
        acc2[2][t].z = fmaf(w2.z, s, acc2[2][t].z);
        acc2[2][t].w = fmaf(w2.w, s, acc2[2][t].w);
      }
      // prefetch o+2 into just-consumed buffers (clamped tail; row 167 re-read)
      int on = o + 2;
      on = on > 167 ? 167 : on;
      #pragma unroll
      for (int cc = 0; cc < 3; ++cc) u[p][cc] = wb_l[(size_t)on * 192 + 64 * cc];
      hb[p][0] = *(const float4*)&hsT[on][tb];
      hb[p][1] = *(const float4*)&hsT[on][tb + 4];
    }

    #pragma unroll
    for (int cc = 0; cc < 3; ++cc)
      #pragma unroll
      for (int t = 0; t < 8; ++t)
        *(float4*)(out + ((size_t)a * T + t0 + tb + t) * C_DIM + cc * 256 + lane * 4)
            = acc2[cc][t];
  }
}

// loss = 2 * cv2(counts)  (importance == load == counts when K=1, gate==1.0)
__global__ void loss_k(const unsigned int* __restrict__ counts,
                       float* __restrict__ out, int T) {
  if (threadIdx.x == 0) {
    float c[7], mean = 0.f;
    #pragma unroll
    for (int e = 0; e < 7; ++e) { c[e] = (float)counts[e]; mean += c[e]; }
    mean *= (1.f / 7.f);
    float var = 0.f;
    #pragma unroll
    for (int e = 0; e < 7; ++e) { const float d = c[e] - mean; var += d * d; }
    var *= (1.f / 6.f);  // ddof=1
    out[(size_t)3 * T * C_DIM] = 2.f * (var / (mean * mean + 1e-10f));
  }
}

extern "C" void kernel_launch(void* const* d_in, const int* in_sizes, int n_in,
                              void* d_out, int out_size, void* d_ws, size_t ws_size,
                              hipStream_t stream) {
  const float* x  = (const float*)d_in[0];
  const float* wg = (const float*)d_in[1];
  const float* Wa = (const float*)d_in[2];
  const float* Wb = (const float*)d_in[3];
  float* out = (float*)d_out;

  unsigned int* counts = (unsigned int*)d_ws;
  float4* waT4 = (float4*)((char*)d_ws + 1024);
  float4* wbT4 = (float4*)((char*)d_ws + 590848);

  const int T = in_sizes[0] / C_DIM;  // 16384

  hipMemsetAsync(counts, 0, 8 * sizeof(unsigned int), stream);
  transpose_wa<<<dim3(144), dim3(256), 0, stream>>>(Wa, wg, waT4);
  transpose_wb<<<dim3(126), dim3(256), 0, stream>>>(Wb, wbT4);
  moe_main<<<dim3(T / 32), dim3(256), 0, stream>>>(x, waT4, wbT4, out, counts, T);
  loss_k<<<dim3(1), dim3(64), 0, stream>>>(counts, out, T);
}